// Round 5
// baseline (2340.396 us; speedup 1.0000x reference)
//
#include <hip/hip_runtime.h>
#include <stdint.h>

typedef __bf16 bf16_t;
typedef __bf16 bf16x8 __attribute__((ext_vector_type(8)));
typedef float floatx16 __attribute__((ext_vector_type(16)));
typedef unsigned int u32;
typedef unsigned long long u64;

#define NPROD 64   // Gx producer WGs
#define H1R   8    // h1 ring depth
#define SST   592  // L0 stage row stride (conflict-free b128 reads)
#define ZST   1104 // L1 z-tile row stride
#define FP    32   // flag padding: 32 u32 = 128 B per flag line

struct KParams {
  const int* tok;
  const float* emb;
  const float* W1[4]; const float* b1[4];
  const float* W2[4]; const float* b2[4];
  const float* Wd; const float* bd; const float* Wout; const float* bout;
  float* out;
  u64* h1;           // ring: 8 x [64][256] bf16 (4096 u64 per slab)
  u64* h2;           // ring: 2 x [64][256] bf16
  u32* fl0;          // 64 per-(L0 WG,wave) flags: s+1 => that wave's h1[s] slice drained
  u32* fl1;          // 128 per-(L1 WG,wave) flags: s+1 => that wave's h2[s] slice drained
  u32* fl0g;         // 64 per-(L0 WG,wave): gx[s] consumed heartbeat
  u32* pflags;       // 512 one-shot: gx[s] ready
  float* dstage;     // [64][128] fp32
  bf16_t* w1bf;      // [20][1024][16] fragment-ordered x-weights (bf16)
  float* gx;         // ring: R slabs of [64][1024] fp32
  int R;
};

__device__ __forceinline__ float sigf(float x) { return 1.f / (1.f + __expf(-x)); }
__device__ __forceinline__ float tanhf_fast(float x) { return 1.f - 2.f / (__expf(2.f * x) + 1.f); }

__device__ __forceinline__ u32 pack2(float a, float b) {
  uint16_t x = __builtin_bit_cast(uint16_t, (bf16_t)a);
  uint16_t y = __builtin_bit_cast(uint16_t, (bf16_t)b);
  return ((u32)y << 16) | (u32)x;
}
__device__ __forceinline__ float2 u2f2(u64 v) { union { u64 u; float2 f; } x; x.u = v; return x.f; }

// relaxed agent-scope ops: bypass L1/L2, coherent at LLC
__device__ __forceinline__ u32  ald32(const u32* p) { return __hip_atomic_load(p, __ATOMIC_RELAXED, __HIP_MEMORY_SCOPE_AGENT); }
__device__ __forceinline__ void ast32(u32* p, u32 v) { __hip_atomic_store(p, v, __ATOMIC_RELAXED, __HIP_MEMORY_SCOPE_AGENT); }
__device__ __forceinline__ u64  ald64(const u64* p) { return __hip_atomic_load(p, __ATOMIC_RELAXED, __HIP_MEMORY_SCOPE_AGENT); }

// drain this wave's outstanding vmem (stores acked at LLC -> safe to publish flag)
__device__ __forceinline__ void vdrain() {
  asm volatile("s_waitcnt vmcnt(0)" ::: "memory");
  __builtin_amdgcn_sched_barrier(0);
}

// wave-wide min of a u32
__device__ __forceinline__ u32 wmin(u32 f) {
#pragma unroll
  for (int d = 1; d < 64; d <<= 1) { u32 o = (u32)__shfl_xor((int)f, d); f = o < f ? o : f; }
  return f;
}

// batched gx-ready watermark: advances gxok by up to 16 per refresh
__device__ __forceinline__ void gx_scan(const KParams& p, int l, int& gxok) {
  int base = gxok + 1;
  u32 ok = 0u;
  if (l < 16) { int idx = base + l; ok = (idx >= 512) ? 1u : (ald32(p.pflags + (size_t)idx * FP) ? 1u : 0u); }
  u64 m = __ballot(ok != 0u);
  int t = (int)__builtin_ctzll(~m);
  gxok = base + t - 1;
}

// ---------------- Layer 0: 16 WGs, each owns 16 units (64 gate cols) ----------
__device__ void run_l0(const KParams& p, int sub, char* abuf, float* cst, float* biasl)
{
  const int tid = threadIdx.x;
  const int w = tid >> 6, l = tid & 63, q = l >> 5, lr = l & 31;
  const int mh = w & 1, nh = w >> 1;

  if (tid < 64) biasl[tid] = p.b1[tid >> 4][sub * 16 + (tid & 15)];

  // W1 h-part rows 300..555 -> register B-fragments (reused 512x)
  const int c = nh * 32 + lr;
  const float* Wg = p.W1[c >> 4];
  const int un = sub * 16 + (c & 15);
  bf16x8 wf[16];
#pragma unroll
  for (int s2 = 0; s2 < 16; ++s2)
#pragma unroll
    for (int j = 0; j < 8; ++j)
      wf[s2][j] = (bf16_t)Wg[(300 + 16 * s2 + 8 * q + j) * 256 + un];
  __syncthreads();

  float cs[2][2] = {{0.f, 0.f}, {0.f, 0.f}};
  int gxok = -1, ringok = 0;

  for (int s = 0; s < 512; ++s) {
    // amortized guards (usually no poll at all)
    while (ringok < s - 7) {           // h1-ring reuse vs L1 readers (slack 8)
      u32 a = ald32(p.fl1 + l * FP), b = ald32(p.fl1 + (l + 64) * FP);
      ringok = (int)wmin(a < b ? a : b);
    }
    while (gxok < s) gx_scan(p, l, gxok);   // gx[s] ready

    // peer gate: all 64 (WG,wave) slices of h1[s-1] drained (all waves poll)
    for (;;) { u32 f = ald32(p.fl0 + l * FP); if (__all(f >= (u32)s)) break; }
    __atomic_signal_fence(__ATOMIC_ACQUIRE);

    // gx[s] loads (consumed at cell; drain at bar1 in parallel with h1)
    const float* slab = p.gx + (size_t)(s % p.R) * 65536u;
    u64 g[2][4];
#pragma unroll
    for (int kk = 0; kk < 2; ++kk) {
      int pp = tid + 256 * kk, b = pp >> 3, u2 = (pp & 7) * 2;
      const float* gb = slab + b * 1024 + sub * 64 + u2;
      g[kk][0] = ald64((const u64*)gb);
      g[kk][1] = ald64((const u64*)(gb + 16));
      g[kk][2] = ald64((const u64*)(gb + 32));
      g[kk][3] = ald64((const u64*)(gb + 48));
    }
    // h1[s-1] bulk load + LDS stage
    {
      const u64* hp = p.h1 + (size_t)((s + H1R - 1) & (H1R - 1)) * 4096;
      u64 tmp[16];
#pragma unroll
      for (int t = 0; t < 16; ++t) tmp[t] = ald64(hp + tid + 256 * t);
#pragma unroll
      for (int t = 0; t < 16; ++t) {
        int i = tid + 256 * t, b = i >> 6, cc = i & 63;
        *(u64*)(abuf + b * SST + cc * 8) = tmp[t];
      }
    }
    __syncthreads();                                   // bar1

    floatx16 acc;
#pragma unroll
    for (int e = 0; e < 16; ++e) acc[e] = 0.f;
    const char* arow = abuf + (mh * 32 + lr) * SST + q * 16;
#pragma unroll
    for (int s2 = 0; s2 < 16; ++s2) {
      bf16x8 af = *(const bf16x8*)(arow + 32 * s2);
      acc = __builtin_amdgcn_mfma_f32_32x32x16_bf16(af, wf[s2], acc, 0, 0, 0);
    }
#pragma unroll
    for (int e = 0; e < 16; ++e) {
      int ri = (e & 3) + 8 * (e >> 2) + 4 * q;
      cst[(mh * 32 + ri) * 68 + nh * 32 + lr] = acc[e];
    }
    __syncthreads();                                   // bar2

    uint16_t* hout = (uint16_t*)(p.h1 + (size_t)(s & (H1R - 1)) * 4096);
#pragma unroll
    for (int kk = 0; kk < 2; ++kk) {
      int pp = tid + 256 * kk, b = pp >> 3, u2 = (pp & 7) * 2;
      float2 pf = *(float2*)&cst[b * 68 +      u2];
      float2 pi = *(float2*)&cst[b * 68 + 16 + u2];
      float2 pg = *(float2*)&cst[b * 68 + 32 + u2];
      float2 po = *(float2*)&cst[b * 68 + 48 + u2];
      float2 gf = u2f2(g[kk][0]), gi = u2f2(g[kk][1]);
      float2 gg = u2f2(g[kk][2]), go = u2f2(g[kk][3]);
      float hv[2];
#pragma unroll
      for (int j = 0; j < 2; ++j) {
        float fj = sigf((j ? pf.y : pf.x) + (j ? gf.y : gf.x) + biasl[u2 + j]);
        float ij = sigf((j ? pi.y : pi.x) + (j ? gi.y : gi.x) + biasl[16 + u2 + j]);
        float gj = tanhf_fast((j ? pg.y : pg.x) + (j ? gg.y : gg.x) + biasl[32 + u2 + j]);
        float oj = sigf((j ? po.y : po.x) + (j ? go.y : go.x) + biasl[48 + u2 + j]);
        float cn = fj * cs[kk][j] + ij * gj;
        cs[kk][j] = cn;
        hv[j] = oj * tanhf_fast(cn);
      }
      ast32((u32*)(hout + b * 256 + sub * 16 + u2), pack2(hv[0], hv[1]));
    }
    vdrain();                              // own wave's h1 stores acked at LLC
    if (l == 0) {
      ast32(p.fl0  + (sub * 4 + w) * FP, (u32)(s + 1));  // per-wave publish
      ast32(p.fl0g + (sub * 4 + w) * FP, (u32)(s + 1));  // producer throttle
    }
  }
}

// ---------------- Layer 1: 32 WGs, 32 batch rows x 16 units, K=512 ------------
// Waves own (N-half, K-quarter) of BOTH z-halves: h1-part MFMAs run while the
// h2[s-1] handoff is still in flight; h2-part accumulates into the same acc.
__device__ void run_l1(const KParams& p, int w2, char* zbuf, float* cst, float* biasl)
{
  const int tid = threadIdx.x;
  const int wv = tid >> 6, l = tid & 63, q = l >> 5, lr = l & 31;
  const int nh = wv & 1, q4 = wv >> 1;
  const int bh = w2 & 1, sub1 = w2 >> 1;

  if (tid < 64) biasl[tid] = p.b2[tid >> 4][sub1 * 16 + (tid & 15)];

  const int c = nh * 32 + lr;
  const float* Wg = p.W2[c >> 4];
  const int un = sub1 * 16 + (c & 15);
  bf16x8 wf[16];   // [0..7]: h1 K-quarter; [8..15]: h2 K-quarter
#pragma unroll
  for (int s2 = 0; s2 < 8; ++s2)
#pragma unroll
    for (int j = 0; j < 8; ++j) {
      wf[s2][j]     = (bf16_t)Wg[(      q4 * 128 + s2 * 16 + q * 8 + j) * 256 + un];
      wf[8 + s2][j] = (bf16_t)Wg[(256 + q4 * 128 + s2 * 16 + q * 8 + j) * 256 + un];
    }
  __syncthreads();

  float cs2[2] = {0.f, 0.f};
  const int cb = tid >> 3, cu = (tid & 7) * 2;
  // own-half gate lane map: 64 per-wave flags of the 16 same-bh L1 WGs
  const int gidx = (2 * (l >> 2) + bh) * 4 + (l & 3);

  // prologue: prefetch h1[0] into registers (slab 0)
  int h1ok = -1;
  while (h1ok < 0) { u32 f = ald32(p.fl0 + l * FP); h1ok = (int)wmin(f) - 1; }
  __atomic_signal_fence(__ATOMIC_ACQUIRE);
  u64 t1[8];
  {
    const u64* hp1 = p.h1 + bh * 2048;
#pragma unroll
    for (int t = 0; t < 8; ++t) t1[t] = ald64(hp1 + tid + 256 * t);
  }

  for (int s = 0; s < 512; ++s) {
    // stage h1[s] (prefetched regs) -> z left half
#pragma unroll
    for (int t = 0; t < 8; ++t) {
      int i = tid + 256 * t, r = i >> 6, cc = i & 63;
      *(u64*)(zbuf + r * ZST + cc * 8) = t1[t];
    }
    __syncthreads();                                   // bar1

    floatx16 acc;
#pragma unroll
    for (int e = 0; e < 16; ++e) acc[e] = 0.f;
    const char* arow1 = zbuf + lr * ZST + q4 * 256 + q * 16;
#pragma unroll
    for (int s2 = 0; s2 < 8; ++s2) {
      bf16x8 af = *(const bf16x8*)(arow1 + 32 * s2);
      acc = __builtin_amdgcn_mfma_f32_32x32x16_bf16(af, wf[s2], acc, 0, 0, 0);
    }

    // h2[s-1] gate (own half only) + bulk load + stage -> z right half
    for (;;) { u32 f = ald32(p.fl1 + gidx * FP); if (__all(f >= (u32)s)) break; }
    __atomic_signal_fence(__ATOMIC_ACQUIRE);
    {
      const u64* hp2 = p.h2 + (size_t)((s + 1) & 1) * 4096 + bh * 2048;
      u64 t2[8];
#pragma unroll
      for (int t = 0; t < 8; ++t) t2[t] = ald64(hp2 + tid + 256 * t);
#pragma unroll
      for (int t = 0; t < 8; ++t) {
        int i = tid + 256 * t, r = i >> 6, cc = i & 63;
        *(u64*)(zbuf + r * ZST + 512 + cc * 8) = t2[t];
      }
    }
    __syncthreads();                                   // bar2

    const char* arow2 = zbuf + lr * ZST + 512 + q4 * 256 + q * 16;
#pragma unroll
    for (int s2 = 0; s2 < 8; ++s2) {
      bf16x8 af = *(const bf16x8*)(arow2 + 32 * s2);
      acc = __builtin_amdgcn_mfma_f32_32x32x16_bf16(af, wf[8 + s2], acc, 0, 0, 0);
    }
#pragma unroll
    for (int e = 0; e < 16; ++e) {
      int ri = (e & 3) + 8 * (e >> 2) + 4 * q;
      cst[q4 * 2176 + ri * 68 + nh * 32 + lr] = acc[e];
    }
    __syncthreads();                                   // bar3

    // cell: sum the two K-quarter planes + bias
    {
      float2 pf = *(float2*)&cst[cb * 68 +      cu];
      float2 pi = *(float2*)&cst[cb * 68 + 16 + cu];
      float2 pg = *(float2*)&cst[cb * 68 + 32 + cu];
      float2 po = *(float2*)&cst[cb * 68 + 48 + cu];
      float2 qf = *(float2*)&cst[2176 + cb * 68 +      cu];
      float2 qi = *(float2*)&cst[2176 + cb * 68 + 16 + cu];
      float2 qg = *(float2*)&cst[2176 + cb * 68 + 32 + cu];
      float2 qo = *(float2*)&cst[2176 + cb * 68 + 48 + cu];
      float hv[2];
#pragma unroll
      for (int j = 0; j < 2; ++j) {
        float fj = sigf((j ? pf.y + qf.y : pf.x + qf.x) + biasl[cu + j]);
        float ij = sigf((j ? pi.y + qi.y : pi.x + qi.x) + biasl[16 + cu + j]);
        float gj = tanhf_fast((j ? pg.y + qg.y : pg.x + qg.x) + biasl[32 + cu + j]);
        float oj = sigf((j ? po.y + qo.y : po.x + qo.x) + biasl[48 + cu + j]);
        float cn = fj * cs2[j] + ij * gj;
        cs2[j] = cn;
        hv[j] = oj * tanhf_fast(cn);
      }
      uint16_t* hout = (uint16_t*)(p.h2 + (size_t)(s & 1) * 4096);
      ast32((u32*)(hout + (bh * 32 + cb) * 256 + sub1 * 16 + cu), pack2(hv[0], hv[1]));
    }
    vdrain();                              // own wave's h2 store acked
    if (l == 0) ast32(p.fl1 + (w2 * 4 + wv) * FP, (u32)(s + 1));

    // prefetch h1[s+1] (after publish: keeps R0's fl1>=s-7 ring guard valid)
    if (s < 511) {
      while (h1ok < s + 1) { u32 f = ald32(p.fl0 + l * FP); h1ok = (int)wmin(f) - 1; }
      const u64* hpn = p.h1 + (size_t)((s + 1) & (H1R - 1)) * 4096 + bh * 2048;
#pragma unroll
      for (int t = 0; t < 8; ++t) t1[t] = ald64(hpn + tid + 256 * t);
    }
  }

  // ---- dense head part 1: 4 cols of d = relu(h2[511] @ Wd + bd) -------------
  for (;;) {
    u32 a = ald32(p.fl1 + l * FP), b = ald32(p.fl1 + (l + 64) * FP);
    if (__all((a >= 512u) && (b >= 512u))) break;
  }
  __atomic_signal_fence(__ATOMIC_ACQUIRE);
  {
    const u64* hp = p.h2 + 4096;           // h2[511] slab 1
    u64 tmp[16];
#pragma unroll
    for (int t = 0; t < 16; ++t) tmp[t] = ald64(hp + tid + 256 * t);
#pragma unroll
    for (int t = 0; t < 16; ++t) {
      int i = tid + 256 * t, b = i >> 6, cc = i & 63;
      *(u64*)(zbuf + b * 520 + cc * 8) = tmp[t];
    }
  }
  __syncthreads();
  {
    int b = tid >> 2, cc = w2 * 4 + (tid & 3);
    const bf16_t* hrow = (const bf16_t*)(zbuf + b * 520);
    float a = p.bd[cc];
#pragma unroll 8
    for (int k = 0; k < 256; ++k) a += (float)hrow[k] * p.Wd[k * 128 + cc];
    ast32((u32*)&p.dstage[b * 128 + cc], __builtin_bit_cast(u32, fmaxf(a, 0.f)));
  }
  vdrain();
  if (l == 0) ast32(p.fl1 + (w2 * 4 + wv) * FP, 600u);

  // ---- final: out = sigmoid(d @ Wout + bout), by L1 WG 0 --------------------
  if (w2 == 0) {
    for (;;) {
      u32 a = ald32(p.fl1 + l * FP), b = ald32(p.fl1 + (l + 64) * FP);
      if (__all((a >= 600u) && (b >= 600u))) break;
    }
    __atomic_signal_fence(__ATOMIC_ACQUIRE);
    if (tid < 64) {
      float a = p.bout[0];
#pragma unroll 8
      for (int cc = 0; cc < 128; ++cc) {
        u32 dv = ald32((u32*)&p.dstage[tid * 128 + cc]);
        a += __builtin_bit_cast(float, dv) * p.Wout[cc];
      }
      p.out[tid] = sigf(a);
    }
  }
}

// ---------------- Gx producers: Gx[s] = x_s @ W1x, K=300 (pad 320) -------------
__device__ void run_prod(const KParams& p, int pw, char* smem)
{
  const int tid = threadIdx.x;
  const int w = tid >> 6, l = tid & 63, q = l >> 5, lr = l & 31;
  const int mh = w & 1, chalf = w >> 1;
  const int R = p.R;

  for (int jj = 0; jj < 512 / NPROD; ++jj) {
    const int s = pw + NPROD * jj;
    if (s >= R) {  // ring throttle on 64 per-wave heartbeats (1/lane)
      if (w == 0) {
        u32 need = (u32)(s - R + 1);
        for (;;) { u32 f = ald32(p.fl0g + l * FP); if (__all(f >= need)) break; }
        __atomic_signal_fence(__ATOMIC_ACQUIRE);
      }
    }
    __syncthreads();
    {
      int b = tid >> 2, qq = tid & 3;
      int tokv = p.tok[b * 512 + s];
      const float4* src = (const float4*)(p.emb + (size_t)tokv * 300);
      char* dst = smem + b * 656;
      for (int j2 = qq; j2 < 75; j2 += 4) {
        float4 v = src[j2];
        *(u32*)(dst + 8 * j2)     = pack2(v.x, v.y);
        *(u32*)(dst + 8 * j2 + 4) = pack2(v.z, v.w);
      }
      for (int i = tid; i < 640; i += 256) {
        int bb = i / 10, cc2 = i % 10;
        *(u32*)(smem + bb * 656 + 600 + cc2 * 4) = 0u;
      }
    }
    __syncthreads();

    bf16x8 afr[20];
    const char* arow = smem + (mh * 32 + lr) * 656 + q * 16;
#pragma unroll
    for (int kt = 0; kt < 20; ++kt) afr[kt] = *(const bf16x8*)(arow + 32 * kt);

    float* slab = p.gx + (size_t)(s % R) * 65536u;
    for (int c2 = 0; c2 < 16; ++c2) {
      int n = (chalf * 16 + c2) * 32 + lr;
      floatx16 acc;
#pragma unroll
      for (int e = 0; e < 16; ++e) acc[e] = 0.f;
#pragma unroll
      for (int kt = 0; kt < 20; ++kt) {
        bf16x8 bf = ((const bf16x8*)p.w1bf)[(kt * 1024 + n) * 2 + q];
        acc = __builtin_amdgcn_mfma_f32_32x32x16_bf16(afr[kt], bf, acc, 0, 0, 0);
      }
#pragma unroll
      for (int e = 0; e < 16; ++e) {
        int ri = (e & 3) + 8 * (e >> 2) + 4 * q;
        ast32((u32*)(slab + (mh * 32 + ri) * 1024 + n), __builtin_bit_cast(u32, acc[e]));
      }
    }
    __syncthreads();                    // drains Gx scoped stores
    if (tid == 0) ast32(&p.pflags[(size_t)s * FP], 1u);
  }
}

__global__ __launch_bounds__(256, 1) void lstm_main(KParams p)
{
  __shared__ __align__(16) char smem[64 * 656];   // L0 stage / L1 z-tile / producer buf / head
  __shared__ float cst[4352];                     // L0: [64][68]; L1: 2 x [32][68]
  __shared__ float biasl[64];
  const int wg = blockIdx.x;
  if (wg < 16)       run_l0(p, wg, smem, cst, biasl);
  else if (wg < 48)  run_l1(p, wg - 16, smem, cst, biasl);
  else               run_prod(p, wg - 48, smem);
}

// One-time: W1 x-part (rows 0..299, zero-pad to 320) -> bf16 fragment order.
__global__ void prep_w(KParams p) {
  int idx = blockIdx.x * 256 + threadIdx.x;
  if (idx >= 20 * 1024 * 16) return;
  int kk = idx & 15, n = (idx >> 4) & 1023, kt = idx >> 14;
  int k = kt * 16 + kk;
  int g = (n >> 4) & 3, su = n >> 6, u = n & 15;
  float v = (k < 300) ? p.W1[g][k * 256 + su * 16 + u] : 0.f;
  p.w1bf[idx] = (bf16_t)v;
}

// Zero h rings + all flags (ws is re-poisoned before every launch).
__global__ void init_ws(u32* ws32) {
  int i = blockIdx.x * 256 + threadIdx.x;
  if (i < 106496) ws32[i] = 0u;   // [0, 425984): h1, h2, fl0, fl1, fl0g, pflags
}

extern "C" void kernel_launch(void* const* d_in, const int* in_sizes, int n_in,
                              void* d_out, int out_size, void* d_ws, size_t ws_size,
                              hipStream_t stream)
{
  KParams p;
  p.tok = (const int*)d_in[0];
  p.emb = (const float*)d_in[1];
  for (int g = 0; g < 4; ++g) {
    p.W1[g] = (const float*)d_in[2 + 2 * g];
    p.b1[g] = (const float*)d_in[3 + 2 * g];
    p.W2[g] = (const float*)d_in[10 + 2 * g];
    p.b2[g] = (const float*)d_in[11 + 2 * g];
  }
  p.Wd   = (const float*)d_in[18];
  p.bd   = (const float*)d_in[19];
  p.Wout = (const float*)d_in[20];
  p.bout = (const float*)d_in[21];
  p.out  = (float*)d_out;

  char* ws = (char*)d_ws;
  p.h1     = (u64*)ws;                    // 8 x 32768 B   -> 262144
  p.h2     = (u64*)(ws + 262144);         // 2 x 32768 B   -> 327680
  p.fl0    = (u32*)(ws + 327680);         // 64 x 128 B    -> 335872
  p.fl1    = (u32*)(ws + 335872);         // 128 x 128 B   -> 352256
  p.fl0g   = (u32*)(ws + 352256);         // 64 x 128 B    -> 360448
  p.pflags = (u32*)(ws + 360448);         // 512 x 128 B   -> 425984
  p.dstage = (float*)(ws + 425984);       // 32768 B       -> 458752
  p.w1bf   = (bf16_t*)(ws + 458752);      // 655360 B      -> 1114112
  p.gx     = (float*)(ws + 1114112);      // ring: R slabs of [64][1024] fp32

  long avail = (long)ws_size - 1114112L;
  int R = (int)(avail / 262144L);
  if (R > 64) R = 64;
  if (R < 1)  R = 1;
  p.R = R;

  hipLaunchKernelGGL(init_ws, dim3(416), dim3(256), 0, stream, (u32*)d_ws);
  hipLaunchKernelGGL(prep_w, dim3(1280), dim3(256), 0, stream, p);
  hipLaunchKernelGGL(lstm_main, dim3(16 + 32 + NPROD), dim3(256), 0, stream, p);
}